// Round 2
// baseline (791.870 us; speedup 1.0000x reference)
//
#include <hip/hip_runtime.h>
#include <math.h>

// Problem: D is [262144, 512] fp32, row-major.
// out = 0.001 * sqrt( sum_j ( sum_i D[i][j]^2 - 1 )^2 )  -- single fp32 scalar.
// Memory-bound: 536.9 MB single read pass -> ~83 us floor at 6.45 TB/s.
// NOTE (R1): measured dur_us=745 is dominated by ~660 us of harness 0xAA
// workspace-poison fills (2x 2.1GB fillBufferAligned @6.4TB/s in rocprof);
// the kernel itself is <330 us and targeted at the ~85 us read floor.

#define NROWS 262144
#define NCOLS 512
#define BLOCKS 2048   // 8 blocks/CU -> 32 waves/CU for max outstanding loads
#define TPB 256

typedef float v4f __attribute__((ext_vector_type(4)));

// Stage 1: per-column sum of squares, accumulated via fp32 atomics into
// colsum[512] (workspace, pre-zeroed by our hipMemsetAsync node).
//
// Layout trick: flat float4 index f has column group (f % 128). With
// nthreads = BLOCKS*TPB = 524288 (a multiple of 128), each thread's
// grid-stride sequence keeps f % 128 == tid % 128 constant -> a single v4f
// accumulator per thread covers fixed columns (tid%128)*4 .. +3.
__global__ __launch_bounds__(TPB) void colsumsq_kernel(
    const float* __restrict__ D, float* __restrict__ colsum) {
  const long total4 = (long)NROWS * NCOLS / 4;        // 2^25 float4s
  const int nthreads = BLOCKS * TPB;                  // 2^19
  const long tid = (long)blockIdx.x * TPB + threadIdx.x;
  const v4f* __restrict__ D4 = (const v4f*)D;

  v4f acc = (v4f){0.f, 0.f, 0.f, 0.f};
  // exactly total4/nthreads = 64 iterations per thread; streaming data,
  // no reuse -> non-temporal loads.
  #pragma unroll 4
  for (long f = tid; f < total4; f += nthreads) {
    v4f v = __builtin_nontemporal_load(D4 + f);
    acc += v * v;
  }

  // Combine the two threads in this block sharing the same column group
  // (t and t+128), then one atomicAdd per column per block.
  __shared__ v4f smem[TPB];
  smem[threadIdx.x] = acc;
  __syncthreads();
  if (threadIdx.x < 128) {
    v4f a = smem[threadIdx.x] + smem[threadIdx.x + 128];
    const int col = threadIdx.x * 4;
    atomicAdd(&colsum[col + 0], a.x);
    atomicAdd(&colsum[col + 1], a.y);
    atomicAdd(&colsum[col + 2], a.z);
    atomicAdd(&colsum[col + 3], a.w);
  }
}

// Stage 2: resid = colsum - 1; out = 0.001 * sqrt(sum(resid^2)). One block.
__global__ __launch_bounds__(NCOLS) void finalize_kernel(
    const float* __restrict__ colsum, float* __restrict__ out) {
  const int t = threadIdx.x;  // 512 threads = 8 waves
  float r = colsum[t] - 1.0f;
  float s = r * r;
  // wave-64 butterfly reduce
  #pragma unroll
  for (int o = 32; o > 0; o >>= 1) s += __shfl_down(s, o, 64);
  __shared__ float red[8];
  if ((t & 63) == 0) red[t >> 6] = s;
  __syncthreads();
  if (t == 0) {
    float tot = 0.f;
    #pragma unroll
    for (int i = 0; i < 8; ++i) tot += red[i];
    out[0] = 0.001f * sqrtf(tot);
  }
}

extern "C" void kernel_launch(void* const* d_in, const int* in_sizes, int n_in,
                              void* d_out, int out_size, void* d_ws, size_t ws_size,
                              hipStream_t stream) {
  const float* D = (const float*)d_in[0];
  float* colsum = (float*)d_ws;           // 512 floats = 2 KB scratch
  float* out = (float*)d_out;

  // ws is poisoned 0xAA before every call -> zero the accumulator.
  hipMemsetAsync(colsum, 0, NCOLS * sizeof(float), stream);

  colsumsq_kernel<<<BLOCKS, TPB, 0, stream>>>(D, colsum);
  finalize_kernel<<<1, NCOLS, 0, stream>>>(colsum, out);
}

// Round 3
// 742.617 us; speedup vs baseline: 1.0663x; 1.0663x over previous
//
#include <hip/hip_runtime.h>
#include <math.h>

// Problem: D is [262144, 512] fp32, row-major.
// out = 0.001 * sqrt( sum_j ( sum_i D[i][j]^2 - 1 )^2 )  -- single fp32 scalar.
// Memory-bound: 536.9 MB single read pass -> ~83 us floor at 6.45 TB/s.
//
// R1 (this config): dur_us=745.5 total, of which ~663 us is two harness 0xAA
//   workspace-poison fills (2x 2.1GB fillBufferAligned @ ~6.4TB/s, visible in
//   rocprof) -> kernel portion ~82 us == the read floor.
// R2 (FAILED): 2048 blocks + __builtin_nontemporal_load -> kernel portion
//   ~130 us (~4.1 TB/s). NT-marked reads bypass L2 request aggregation and
//   cost ~35% of streaming read BW on gfx950. Reverted.

#define NROWS 262144
#define NCOLS 512
#define BLOCKS 1024
#define TPB 256

// Stage 1: per-column sum of squares, accumulated via fp32 atomics into
// colsum[512] (workspace, pre-zeroed by hipMemsetAsync).
//
// Layout trick: flat float4 index f has column group (f % 128). With
// nthreads = BLOCKS*TPB = 262144 (a multiple of 128), each thread's grid-stride
// sequence keeps f % 128 == threadIdx.x % 128 constant -> a single float4
// accumulator per thread covers fixed columns (threadIdx.x%128)*4 .. +3.
__global__ __launch_bounds__(TPB) void colsumsq_kernel(
    const float* __restrict__ D, float* __restrict__ colsum) {
  const long total4 = (long)NROWS * NCOLS / 4;        // 2^25 float4s
  const int nthreads = BLOCKS * TPB;                  // 2^18
  const long tid = (long)blockIdx.x * TPB + threadIdx.x;
  const float4* __restrict__ D4 = (const float4*)D;

  float4 acc = make_float4(0.f, 0.f, 0.f, 0.f);
  // exactly total4/nthreads = 128 iterations per thread
  #pragma unroll 4
  for (long f = tid; f < total4; f += nthreads) {
    float4 v = D4[f];
    acc.x = fmaf(v.x, v.x, acc.x);
    acc.y = fmaf(v.y, v.y, acc.y);
    acc.z = fmaf(v.z, v.z, acc.z);
    acc.w = fmaf(v.w, v.w, acc.w);
  }

  // Combine the two threads in this block sharing the same column group
  // (t and t+128), then one atomicAdd per column per block.
  __shared__ float4 smem[TPB];
  smem[threadIdx.x] = acc;
  __syncthreads();
  if (threadIdx.x < 128) {
    float4 a = smem[threadIdx.x];
    float4 b = smem[threadIdx.x + 128];
    a.x += b.x; a.y += b.y; a.z += b.z; a.w += b.w;
    const int col = threadIdx.x * 4;
    atomicAdd(&colsum[col + 0], a.x);
    atomicAdd(&colsum[col + 1], a.y);
    atomicAdd(&colsum[col + 2], a.z);
    atomicAdd(&colsum[col + 3], a.w);
  }
}

// Stage 2: resid = colsum - 1; out = 0.001 * sqrt(sum(resid^2)). One block.
__global__ __launch_bounds__(NCOLS) void finalize_kernel(
    const float* __restrict__ colsum, float* __restrict__ out) {
  const int t = threadIdx.x;  // 512 threads = 8 waves
  float r = colsum[t] - 1.0f;
  float s = r * r;
  // wave-64 butterfly reduce
  #pragma unroll
  for (int o = 32; o > 0; o >>= 1) s += __shfl_down(s, o, 64);
  __shared__ float red[8];
  if ((t & 63) == 0) red[t >> 6] = s;
  __syncthreads();
  if (t == 0) {
    float tot = 0.f;
    #pragma unroll
    for (int i = 0; i < 8; ++i) tot += red[i];
    out[0] = 0.001f * sqrtf(tot);
  }
}

extern "C" void kernel_launch(void* const* d_in, const int* in_sizes, int n_in,
                              void* d_out, int out_size, void* d_ws, size_t ws_size,
                              hipStream_t stream) {
  const float* D = (const float*)d_in[0];
  float* colsum = (float*)d_ws;           // 512 floats = 2 KB scratch
  float* out = (float*)d_out;

  // ws is poisoned 0xAA before every call -> zero the accumulator.
  hipMemsetAsync(colsum, 0, NCOLS * sizeof(float), stream);

  colsumsq_kernel<<<BLOCKS, TPB, 0, stream>>>(D, colsum);
  finalize_kernel<<<1, NCOLS, 0, stream>>>(colsum, out);
}